// Round 5
// baseline (307.515 us; speedup 1.0000x reference)
//
#include <hip/hip_runtime.h>
#include <hip/hip_bf16.h>

#define NNODES 90112
#define BGRAPH 4096
#define NPG 22
#define DBB 256
#define DNODE 128
#define DPROJ 256
#define DGIN 64
#define DGOUT 128

// ws layout (bf16 elems):
//   [0,        32768)  WTp   [256 cols][128 k]   (w_proj^T)
//   [32768,   622592)  WTg   [768 cols][768 k]   (cols: z|r|h gates; k: z|x_proj|prev_h)
//   [622592,  688128)  WThh  [256 cols][256 k]
// then f32 at byte offset 688128*2: bz[256], br[256], bh[256] (combined biases)
#define WTG_OFF   32768
#define WTHH_OFF  622592
#define WS_BF16_ELEMS 688128

typedef __attribute__((ext_vector_type(8))) short bf16x8;
typedef __attribute__((ext_vector_type(4))) short bf16x4;
typedef __attribute__((ext_vector_type(4))) float f32x4;

__device__ __forceinline__ short f2bf(float f) {
  __hip_bfloat16 h = __float2bfloat16(f);
  return *reinterpret_cast<short*>(&h);
}
__device__ __forceinline__ float bf2f(short s) {
  union { unsigned int u; float f; } c;
  c.u = ((unsigned int)(unsigned short)s) << 16;
  return c.f;
}
__device__ __forceinline__ float fsig(float xv) {
  return __fdividef(1.0f, 1.0f + __expf(-xv));
}
__device__ __forceinline__ float ftanh(float xv) {
  return 1.0f - __fdividef(2.0f, __expf(2.0f * xv) + 1.0f);
}

__global__ void pack_weights(const float* __restrict__ w_proj,
                             const float* __restrict__ W_xz, const float* __restrict__ W_hz,
                             const float* __restrict__ W_xr, const float* __restrict__ W_hr,
                             const float* __restrict__ W_xh, const float* __restrict__ W_hh,
                             const float* __restrict__ b_xz, const float* __restrict__ b_hz,
                             const float* __restrict__ b_xr, const float* __restrict__ b_hr,
                             const float* __restrict__ b_xh, const float* __restrict__ b_hh,
                             __hip_bfloat16* __restrict__ wsb, float* __restrict__ wsf) {
  int i = blockIdx.x * 256 + threadIdx.x;
  if (i < 32768) {
    int c = i >> 7, k = i & 127;                 // WTp[c][k] = w_proj[k][c]
    wsb[i] = __float2bfloat16(w_proj[k * DPROJ + c]);
  } else if (i < WTHH_OFF) {
    int j = i - WTG_OFF;
    int c = j / 768, k = j - c * 768;
    const float* Wx; const float* Wh; int cc;
    if (c < 256)      { Wx = W_xz; Wh = W_hz; cc = c; }
    else if (c < 512) { Wx = W_xr; Wh = W_hr; cc = c - 256; }
    else              { Wx = W_xh; Wh = nullptr; cc = c - 512; }
    float v;
    if (k < 512) v = Wx[k * 256 + cc];
    else         v = Wh ? Wh[(k - 512) * 256 + cc] : 0.0f;
    wsb[i] = __float2bfloat16(v);
  } else if (i < WS_BF16_ELEMS) {
    int j = i - WTHH_OFF;
    int c = j >> 8, k = j & 255;                 // WThh[c][k] = W_hh[k][c]
    wsb[i] = __float2bfloat16(W_hh[k * 256 + c]);
  }
  if (i < 256) {
    wsf[i]       = b_xz[i] + b_hz[i];
    wsf[256 + i] = b_xr[i] + b_hr[i];
    wsf[512 + i] = b_xh[i] + b_hh[i];
  }
}

// fused[b] = [ mean_{22 rows} z , relu(u @ w_glob + b_glob) ]
__global__ void fused_head(const float* __restrict__ z, const float* __restrict__ u,
                           const float* __restrict__ w_glob, const float* __restrict__ b_glob,
                           float* __restrict__ out) {
  int b = blockIdx.x;
  int t = threadIdx.x;  // 128 threads
  __shared__ float us[DGIN];
  if (t < DGIN) us[t] = u[b * DGIN + t];
  __syncthreads();
  const float* zb = z + (size_t)b * NPG * DBB;
  #pragma unroll
  for (int half = 0; half < 2; ++half) {
    int c = t + half * 128;
    float s = 0.f;
    #pragma unroll
    for (int r = 0; r < NPG; ++r) s += zb[r * DBB + c];
    out[(size_t)b * 384 + c] = s * (1.0f / NPG);
  }
  float acc = b_glob[t];
  #pragma unroll
  for (int k = 0; k < DGIN; ++k) acc += us[k] * w_glob[k * DGOUT + t];
  out[(size_t)b * 384 + 256 + t] = fmaxf(acc, 0.f);
}

#define MFMA16(a, b, c) __builtin_amdgcn_mfma_f32_16x16x32_bf16(a, b, c, 0, 0, 0)

// Fused GRU body: 64 rows/block, 1024 threads = 16 waves, each wave owns 16
// weight-cols x 64 rows. Gate sweeps software-pipelined (depth-2 register
// double-buffer): step s+1 loads issued before step s's MFMAs.
__global__ __launch_bounds__(1024)
void grnn_main(const float* __restrict__ z, const float* __restrict__ x,
               const float* __restrict__ prev_h, const float* __restrict__ b_proj,
               const __hip_bfloat16* __restrict__ wsb, const float* __restrict__ wsf,
               float* __restrict__ h_out) {
  __shared__ __align__(16) __hip_bfloat16 Xs[64 * 128];
  __shared__ __align__(16) __hip_bfloat16 Zs[64 * 256];
  __shared__ __align__(16) __hip_bfloat16 XPs[64 * 256];
  __shared__ __align__(16) __hip_bfloat16 PHs[64 * 256];
  __shared__ __align__(16) __hip_bfloat16 Ts[64 * 256];   // T = ph*sigmoid(Ar)

  const int r0   = blockIdx.x * 64;
  const int tid  = threadIdx.x;
  const int wid  = tid >> 6;          // 0..15
  const int lane = tid & 63;
  const int l15  = lane & 15;
  const int lg   = lane >> 4;         // 0..3
  const int l7   = l15 & 7;
  const int c0   = wid * 16;          // wave's 16-col slice
  const int cgrp = (c0 >> 3) + (lg >> 1);   // granule of lane's 4-col quad
  const int lgl  = (lg & 1) * 4;            // elem offset within granule

  // ---- P0: stage x -> Xs ([64][128], 16B-granule XOR swizzle) ----
  {
    int row = tid >> 4, c8 = tid & 15;
    const float* p = x + (size_t)(r0 + row) * DNODE + c8 * 8;
    float4 f0 = *(const float4*)p;
    float4 f1 = *(const float4*)(p + 4);
    bf16x8 o;
    o[0]=f2bf(f0.x); o[1]=f2bf(f0.y); o[2]=f2bf(f0.z); o[3]=f2bf(f0.w);
    o[4]=f2bf(f1.x); o[5]=f2bf(f1.y); o[6]=f2bf(f1.z); o[7]=f2bf(f1.w);
    *(bf16x8*)&Xs[row * 128 + (c8 ^ (row & 7)) * 8] = o;
  }
  __syncthreads();

  // ---- P1: issue z+ph loads, x_proj GEMM under them, then LDS writes ----
  float4 slz[4], slp[4];
  #pragma unroll
  for (int i = 0; i < 2; ++i) {
    int g = tid + i * 1024;
    int row = g >> 5, c8 = g & 31;
    const float* pz = z + (size_t)(r0 + row) * DBB + c8 * 8;
    const float* pp = prev_h + (size_t)(r0 + row) * DBB + c8 * 8;
    slz[2 * i]     = *(const float4*)pz;
    slz[2 * i + 1] = *(const float4*)(pz + 4);
    slp[2 * i]     = *(const float4*)pp;
    slp[2 * i + 1] = *(const float4*)(pp + 4);
  }
  f32x4 accp[4] = {};
  {
    const __hip_bfloat16* wp0 = wsb + (size_t)(c0 + l15) * DNODE + lg * 8;
    bf16x8 wpv[2];
    wpv[0] = *(const bf16x8*)(wp0);
    bf16x8 apv[2][4];
    #pragma unroll
    for (int rt = 0; rt < 4; ++rt)
      apv[0][rt] = *(const bf16x8*)&Xs[(rt * 16 + l15) * 128 + (lg ^ l7) * 8];
    #pragma unroll
    for (int kb = 0; kb < 4; ++kb) {
      const int cb = kb & 1, nb = cb ^ 1;
      if (kb < 3) {
        wpv[nb] = *(const bf16x8*)(wp0 + (kb + 1) * 32);
        const int gk = (kb + 1) * 4 + lg;
        #pragma unroll
        for (int rt = 0; rt < 4; ++rt)
          apv[nb][rt] = *(const bf16x8*)&Xs[(rt * 16 + l15) * 128 + (gk ^ l7) * 8];
      }
      __builtin_amdgcn_s_setprio(1);
      #pragma unroll
      for (int rt = 0; rt < 4; ++rt)
        accp[rt] = MFMA16(wpv[cb], apv[cb][rt], accp[rt]);
      __builtin_amdgcn_s_setprio(0);
    }
  }
  #pragma unroll
  for (int i = 0; i < 2; ++i) {
    int g = tid + i * 1024;
    int row = g >> 5, c8 = g & 31;
    int off = row * 256 + (c8 ^ (row & 7)) * 8;
    float4 f0 = slz[2 * i], f1 = slz[2 * i + 1];
    bf16x8 o;
    o[0]=f2bf(f0.x); o[1]=f2bf(f0.y); o[2]=f2bf(f0.z); o[3]=f2bf(f0.w);
    o[4]=f2bf(f1.x); o[5]=f2bf(f1.y); o[6]=f2bf(f1.z); o[7]=f2bf(f1.w);
    *(bf16x8*)&Zs[off] = o;
    f0 = slp[2 * i]; f1 = slp[2 * i + 1];
    o[0]=f2bf(f0.x); o[1]=f2bf(f0.y); o[2]=f2bf(f0.z); o[3]=f2bf(f0.w);
    o[4]=f2bf(f1.x); o[5]=f2bf(f1.y); o[6]=f2bf(f1.z); o[7]=f2bf(f1.w);
    *(bf16x8*)&PHs[off] = o;
  }
  {
    float4 bp4 = *(const float4*)&b_proj[c0 + lg * 4];
    #pragma unroll
    for (int rt = 0; rt < 4; ++rt) {
      int r = rt * 16 + l15;
      bf16x4 o;
      o[0] = f2bf(fmaxf(accp[rt][0] + bp4.x, 0.f));
      o[1] = f2bf(fmaxf(accp[rt][1] + bp4.y, 0.f));
      o[2] = f2bf(fmaxf(accp[rt][2] + bp4.z, 0.f));
      o[3] = f2bf(fmaxf(accp[rt][3] + bp4.w, 0.f));
      *(bf16x4*)&XPs[r * 256 + ((cgrp ^ (r & 7)) * 8) + lgl] = o;
    }
  }

  // Prefetch gates step-0 weights before the barrier (global, no LDS dep)
  const __hip_bfloat16* wbase = wsb + WTG_OFF + (size_t)(c0 + l15) * 768 + lg * 8;
  f32x4 accz[4] = {}, accr[4] = {}, acch[4] = {};
  bf16x8 wzb[2], wrb[2], whb[2];
  wzb[0] = *(const bf16x8*)(wbase);
  wrb[0] = *(const bf16x8*)(wbase + 196608);
  whb[0] = *(const bf16x8*)(wbase + 393216);
  __syncthreads();

  // ---- P2: unified pipelined gate sweep: 24 steps (3 sources x 8 kb) ----
  {
    const __hip_bfloat16* const tp[3] = { Zs, XPs, PHs };
    bf16x8 actb[2][4];
    #pragma unroll
    for (int rt = 0; rt < 4; ++rt)
      actb[0][rt] = *(const bf16x8*)(tp[0] + (rt * 16 + l15) * 256 + ((lg ^ l7) * 8));
    #pragma unroll
    for (int s = 0; s < 24; ++s) {
      const int cb = s & 1, nb = cb ^ 1;
      if (s < 23) {
        const int sn = s + 1, ksn = sn >> 3, kbn = sn & 7;
        const __hip_bfloat16* wp = wbase + ksn * 256 + kbn * 32;
        wzb[nb] = *(const bf16x8*)(wp);
        wrb[nb] = *(const bf16x8*)(wp + 196608);
        if (ksn < 2) whb[nb] = *(const bf16x8*)(wp + 393216);
        const int gkn = (kbn * 4 + lg) ^ l7;
        const __hip_bfloat16* t_ = tp[ksn];
        #pragma unroll
        for (int rt = 0; rt < 4; ++rt)
          actb[nb][rt] = *(const bf16x8*)(t_ + (rt * 16 + l15) * 256 + gkn * 8);
      }
      const int ks = s >> 3;
      __builtin_amdgcn_s_setprio(1);
      #pragma unroll
      for (int rt = 0; rt < 4; ++rt) {
        accz[rt] = MFMA16(wzb[cb], actb[cb][rt], accz[rt]);
        accr[rt] = MFMA16(wrb[cb], actb[cb][rt], accr[rt]);
        if (ks < 2) acch[rt] = MFMA16(whb[cb], actb[cb][rt], acch[rt]);
      }
      __builtin_amdgcn_s_setprio(0);
    }
  }

  // T = ph * sigmoid(A_r + br) -> Ts (no barrier needed: Ts unread until sync)
  {
    float4 br4 = *(const float4*)&wsf[256 + c0 + lg * 4];
    #pragma unroll
    for (int rt = 0; rt < 4; ++rt) {
      int r = rt * 16 + l15;
      int off = r * 256 + ((cgrp ^ (r & 7)) * 8) + lgl;
      bf16x4 p4 = *(const bf16x4*)&PHs[off];
      bf16x4 o;
      o[0] = f2bf(bf2f(p4[0]) * fsig(accr[rt][0] + br4.x));
      o[1] = f2bf(bf2f(p4[1]) * fsig(accr[rt][1] + br4.y));
      o[2] = f2bf(bf2f(p4[2]) * fsig(accr[rt][2] + br4.z));
      o[3] = f2bf(bf2f(p4[3]) * fsig(accr[rt][3] + br4.w));
      *(bf16x4*)&Ts[off] = o;
    }
  }
  // Prefetch Whh step-0 weights before the barrier
  const __hip_bfloat16* hbase = wsb + WTHH_OFF + (size_t)(c0 + l15) * 256 + lg * 8;
  bf16x8 hwv[2];
  hwv[0] = *(const bf16x8*)(hbase);
  __syncthreads();

  // ---- P3: acch += T @ W_hh (pipelined, 8 steps, reads Ts) ----
  {
    bf16x8 hav[2][4];
    #pragma unroll
    for (int rt = 0; rt < 4; ++rt)
      hav[0][rt] = *(const bf16x8*)&Ts[(rt * 16 + l15) * 256 + ((lg ^ l7) * 8)];
    #pragma unroll
    for (int s = 0; s < 8; ++s) {
      const int cb = s & 1, nb = cb ^ 1;
      if (s < 7) {
        hwv[nb] = *(const bf16x8*)(hbase + (s + 1) * 32);
        const int gkn = ((s + 1) * 4 + lg) ^ l7;
        #pragma unroll
        for (int rt = 0; rt < 4; ++rt)
          hav[nb][rt] = *(const bf16x8*)&Ts[(rt * 16 + l15) * 256 + gkn * 8];
      }
      __builtin_amdgcn_s_setprio(1);
      #pragma unroll
      for (int rt = 0; rt < 4; ++rt)
        acch[rt] = MFMA16(hwv[cb], hav[cb][rt], acch[rt]);
      __builtin_amdgcn_s_setprio(0);
    }
  }

  // ---- epilogue: h = Z*ph + (1-Z)*tanh(A_h); coalesced float4 stores ----
  {
    float4 bz4 = *(const float4*)&wsf[c0 + lg * 4];
    float4 bh4 = *(const float4*)&wsf[512 + c0 + lg * 4];
    #pragma unroll
    for (int rt = 0; rt < 4; ++rt) {
      int r = rt * 16 + l15;
      bf16x4 p4 = *(const bf16x4*)&PHs[r * 256 + ((cgrp ^ (r & 7)) * 8) + lgl];
      float4 hv;
      float zg = fsig(accz[rt][0] + bz4.x);
      hv.x = zg * bf2f(p4[0]) + (1.f - zg) * ftanh(acch[rt][0] + bh4.x);
      zg = fsig(accz[rt][1] + bz4.y);
      hv.y = zg * bf2f(p4[1]) + (1.f - zg) * ftanh(acch[rt][1] + bh4.y);
      zg = fsig(accz[rt][2] + bz4.z);
      hv.z = zg * bf2f(p4[2]) + (1.f - zg) * ftanh(acch[rt][2] + bh4.z);
      zg = fsig(accz[rt][3] + bz4.w);
      hv.w = zg * bf2f(p4[3]) + (1.f - zg) * ftanh(acch[rt][3] + bh4.w);
      *(float4*)&h_out[(size_t)(r0 + r) * DBB + c0 + lg * 4] = hv;
    }
  }
}

extern "C" void kernel_launch(void* const* d_in, const int* in_sizes, int n_in,
                              void* d_out, int out_size, void* d_ws, size_t ws_size,
                              hipStream_t stream) {
  const float* z      = (const float*)d_in[0];
  const float* u      = (const float*)d_in[1];
  const float* x      = (const float*)d_in[2];
  const float* prev_h = (const float*)d_in[6];
  const float* w_proj = (const float*)d_in[7];
  const float* b_proj = (const float*)d_in[8];
  const float* w_glob = (const float*)d_in[9];
  const float* b_glob = (const float*)d_in[10];
  const float* W_xz   = (const float*)d_in[11];
  const float* b_xz   = (const float*)d_in[12];
  const float* W_hz   = (const float*)d_in[13];
  const float* b_hz   = (const float*)d_in[14];
  const float* W_xr   = (const float*)d_in[15];
  const float* b_xr   = (const float*)d_in[16];
  const float* W_hr   = (const float*)d_in[17];
  const float* b_hr   = (const float*)d_in[18];
  const float* W_xh   = (const float*)d_in[19];
  const float* b_xh   = (const float*)d_in[20];
  const float* W_hh   = (const float*)d_in[21];
  const float* b_hh   = (const float*)d_in[22];

  __hip_bfloat16* wsb = (__hip_bfloat16*)d_ws;
  float* wsf = (float*)((char*)d_ws + (size_t)WS_BF16_ELEMS * 2);

  float* fused = (float*)d_out;
  float* h_out = fused + (size_t)BGRAPH * 384;

  pack_weights<<<dim3(WS_BF16_ELEMS / 256), dim3(256), 0, stream>>>(
      w_proj, W_xz, W_hz, W_xr, W_hr, W_xh, W_hh,
      b_xz, b_hz, b_xr, b_hr, b_xh, b_hh, wsb, wsf);

  // head first: warms L3 with z before the main pass
  fused_head<<<dim3(BGRAPH), dim3(128), 0, stream>>>(z, u, w_glob, b_glob, fused);

  grnn_main<<<dim3(NNODES / 64), dim3(1024), 0, stream>>>(
      z, x, prev_h, b_proj, wsb, wsf, h_out);
}